// Round 2
// baseline (771.709 us; speedup 1.0000x reference)
//
#include <hip/hip_runtime.h>

// LSTM scan: S=2048, B=4096, IN=1, H=10.
// Design: 16 lanes per batch element; lane j (j<10) owns hidden unit j.
//   - gate matvec: 4 gates x (10 h + x + bias) FMAs per lane per step
//   - activations: v_exp_f32 / v_rcp_f32 based sigmoid/tanh
//   - h broadcast via 64B LDS row per group (same-wave DS ops are in-order:
//     no barrier needed in the 2048-step loop)
//   - fc dot computed redundantly on all lanes from the freshly-read h;
//     lane q==0 stores (4 consecutive floats per wave -> 1 transaction)
// Grid: 256 blocks x 256 threads = 1024 waves = 1 wave/SIMD on 256 CUs.

#define SEQ   2048
#define BATCH 4096
#define HID   10

__device__ __forceinline__ float fast_sigmoid(float v) {
    // 1/(1 + 2^(-v*log2e))
    float e = __builtin_amdgcn_exp2f(-1.44269504088896f * v);
    return __builtin_amdgcn_rcpf(1.0f + e);
}

__device__ __forceinline__ float fast_tanh(float v) {
    // 2*sigmoid(2v) - 1
    float e = __builtin_amdgcn_exp2f(-2.88539008177793f * v);
    return __builtin_fmaf(2.0f, __builtin_amdgcn_rcpf(1.0f + e), -1.0f);
}

__global__ __launch_bounds__(256) void lstm_scan_kernel(
    const float* __restrict__ x,     // [S, B]
    const float* __restrict__ w_ih,  // [40, 1]
    const float* __restrict__ w_hh,  // [40, 10]
    const float* __restrict__ b_ih,  // [40]
    const float* __restrict__ b_hh,  // [40]
    const float* __restrict__ fc_w,  // [10]
    const float* __restrict__ fc_b,  // [1]
    float* __restrict__ out)         // [S, B]
{
    __shared__ float h_sh[16][16];   // [group][padded h row], 64B rows

    const int tid = threadIdx.x;
    const int grp = tid >> 4;        // 0..15 group within block
    const int q   = tid & 15;        // lane within group
    const int b   = (blockIdx.x << 4) + grp;   // batch element
    const int qq  = (q < 10) ? q : 0;          // lanes 10..15 duplicate j=0

    // ---- load per-lane weights (rows qq, 10+qq, 20+qq, 30+qq) ----
    float whh[4][10];
    float wih[4], bias[4];
#pragma unroll
    for (int g = 0; g < 4; ++g) {
        const int row = g * 10 + qq;
#pragma unroll
        for (int k = 0; k < 10; ++k) whh[g][k] = w_hh[row * 10 + k];
        wih[g]  = w_ih[row];
        bias[g] = b_ih[row] + b_hh[row];
    }
    float fw[10];
#pragma unroll
    for (int k = 0; k < 10; ++k) fw[k] = fc_w[k];
    const float fb = fc_b[0];

    // ---- state ----
    float c = 0.0f;
    float ha[10];
#pragma unroll
    for (int k = 0; k < 10; ++k) ha[k] = 0.0f;

    size_t idx = (size_t)b;
    float xv = x[idx];

#pragma unroll 1
    for (int t = 0; t < SEQ; ++t) {
        // prefetch next x (issued early, independent of the LDS chain)
        const size_t nidx = idx + BATCH;
        const float xv_next = x[(t + 1 < SEQ) ? nidx : idx];

        // gates = bias + w_ih*x + w_hh @ h
        float g0 = __builtin_fmaf(wih[0], xv, bias[0]);
        float g1 = __builtin_fmaf(wih[1], xv, bias[1]);
        float g2 = __builtin_fmaf(wih[2], xv, bias[2]);
        float g3 = __builtin_fmaf(wih[3], xv, bias[3]);
#pragma unroll
        for (int k = 0; k < 10; ++k) {
            g0 = __builtin_fmaf(whh[0][k], ha[k], g0);
            g1 = __builtin_fmaf(whh[1][k], ha[k], g1);
            g2 = __builtin_fmaf(whh[2][k], ha[k], g2);
            g3 = __builtin_fmaf(whh[3][k], ha[k], g3);
        }

        const float iv = fast_sigmoid(g0);
        const float fv = fast_sigmoid(g1);
        const float gv = fast_tanh(g2);
        const float ov = fast_sigmoid(g3);

        c = __builtin_fmaf(fv, c, iv * gv);
        const float hv = ov * fast_tanh(c);

        // publish h_j, then read the full h row (same wave -> in-order DS,
        // no barrier; lanes 10..15 write the padding, never read)
        h_sh[grp][q] = hv;
        const float4 h03 = *reinterpret_cast<const float4*>(&h_sh[grp][0]);
        const float4 h47 = *reinterpret_cast<const float4*>(&h_sh[grp][4]);
        const float2 h89 = *reinterpret_cast<const float2*>(&h_sh[grp][8]);
        ha[0] = h03.x; ha[1] = h03.y; ha[2] = h03.z; ha[3] = h03.w;
        ha[4] = h47.x; ha[5] = h47.y; ha[6] = h47.z; ha[7] = h47.w;
        ha[8] = h89.x; ha[9] = h89.y;

        // y_t = fc_w . h_t + fc_b  (redundant on all lanes; lane 0 stores)
        float y = fb;
#pragma unroll
        for (int k = 0; k < 10; ++k) y = __builtin_fmaf(fw[k], ha[k], y);
        if (q == 0) out[idx] = y;

        xv  = xv_next;
        idx = nidx;
    }
}

extern "C" void kernel_launch(void* const* d_in, const int* in_sizes, int n_in,
                              void* d_out, int out_size, void* d_ws, size_t ws_size,
                              hipStream_t stream) {
    const float* x    = (const float*)d_in[0];
    const float* w_ih = (const float*)d_in[1];
    const float* w_hh = (const float*)d_in[2];
    const float* b_ih = (const float*)d_in[3];
    const float* b_hh = (const float*)d_in[4];
    const float* fc_w = (const float*)d_in[5];
    const float* fc_b = (const float*)d_in[6];
    float* out = (float*)d_out;

    dim3 grid(BATCH / 16);   // 256 blocks, 16 batch elements (groups) each
    dim3 block(256);
    lstm_scan_kernel<<<grid, block, 0, stream>>>(x, w_ih, w_hh, b_ih, b_hh,
                                                 fc_w, fc_b, out);
}

// Round 3
// 747.078 us; speedup vs baseline: 1.0330x; 1.0330x over previous
//
#include <hip/hip_runtime.h>

// LSTM scan: S=2048, B=4096, IN=1, H=10.
// 16 lanes per batch element; lane j owns hidden unit j. Wave64 = 4 elems.
// Round-3 changes vs round-2 (771us, VALUBusy 44%, trans ~22cy each):
//  - weights pre-scaled by -log2e / -2log2e: act = rcp(1+exp2(g)), no glue muls
//  - gate matvec packed as float2 (i,f) / (g,o) -> v_pk_fma_f32 (44->22 FMA instr)
//  - fc deferred one step: y(t-1) computed from live ha regs in the tanh(c) shadow
//  - depth-2 x prefetch via 2x unroll (iter shrinks below HBM latency)

#define SEQ   2048
#define BATCH 4096
#define HID   10

typedef float v2f __attribute__((ext_vector_type(2)));

__device__ __forceinline__ float rcpf(float v) { return __builtin_amdgcn_rcpf(v); }
__device__ __forceinline__ float ex2(float v)  { return __builtin_amdgcn_exp2f(v); }

__global__ __launch_bounds__(256) void lstm_scan_kernel(
    const float* __restrict__ x,     // [S, B]
    const float* __restrict__ w_ih,  // [40, 1]
    const float* __restrict__ w_hh,  // [40, 10]
    const float* __restrict__ b_ih,  // [40]
    const float* __restrict__ b_hh,  // [40]
    const float* __restrict__ fc_w,  // [10]
    const float* __restrict__ fc_b,  // [1]
    float* __restrict__ out)         // [S, B]
{
    __shared__ float h_sh[16][16];   // [group][padded h row], 64B rows

    const int tid = threadIdx.x;
    const int grp = tid >> 4;        // 0..15 group within block
    const int q   = tid & 15;        // lane within group
    const int b   = (blockIdx.x << 4) + grp;   // batch element
    const int qq  = (q < 10) ? q : 0;          // lanes 10..15 duplicate j=0

    const float L2E = 1.44269504088896f;
    // rows: i=qq, f=10+qq, g=20+qq, o=30+qq. Pre-scale: sigmoid rows by -L2E,
    // tanh (g) row by -2*L2E, so activation is rcp(1+exp2(gate)).
    const int r0 = qq, r1 = 10 + qq, r2 = 20 + qq, r3 = 30 + qq;
    const float s0 = -L2E, s1 = -L2E, s2 = -2.0f * L2E, s3 = -L2E;

    v2f w01[10], w23[10];
#pragma unroll
    for (int k = 0; k < 10; ++k) {
        w01[k] = (v2f){s0 * w_hh[r0 * 10 + k], s1 * w_hh[r1 * 10 + k]};
        w23[k] = (v2f){s2 * w_hh[r2 * 10 + k], s3 * w_hh[r3 * 10 + k]};
    }
    const v2f wih01  = (v2f){s0 * w_ih[r0], s1 * w_ih[r1]};
    const v2f wih23  = (v2f){s2 * w_ih[r2], s3 * w_ih[r3]};
    const v2f bias01 = (v2f){s0 * (b_ih[r0] + b_hh[r0]), s1 * (b_ih[r1] + b_hh[r1])};
    const v2f bias23 = (v2f){s2 * (b_ih[r2] + b_hh[r2]), s3 * (b_ih[r3] + b_hh[r3])};

    float fw[10];
#pragma unroll
    for (int k = 0; k < 10; ++k) fw[k] = fc_w[k];
    const float fb = fc_b[0];

    float c = 0.0f;
    float ha[10];
#pragma unroll
    for (int k = 0; k < 10; ++k) ha[k] = 0.0f;

    // depth-2 x prefetch state
    size_t ix = (size_t)b;               // x index of current even step
    float xA = x[ix];                    // x(t)
    float xB = x[ix + BATCH];            // x(t+1)

#define BODY(XV, IDX, TT)                                                     \
    {                                                                         \
        const v2f xv2 = (v2f)(XV);                                            \
        v2f ga01 = xv2 * wih01 + bias01;                                      \
        v2f ga23 = xv2 * wih23 + bias23;                                      \
        v2f gb01 = (v2f)(0.0f);                                               \
        v2f gb23 = (v2f)(0.0f);                                               \
        _Pragma("unroll")                                                     \
        for (int k = 0; k < 10; k += 2) {                                     \
            const v2f he = (v2f)(ha[k]);                                      \
            ga01 = he * w01[k] + ga01;                                        \
            ga23 = he * w23[k] + ga23;                                        \
        }                                                                     \
        _Pragma("unroll")                                                     \
        for (int k = 1; k < 10; k += 2) {                                     \
            const v2f ho = (v2f)(ha[k]);                                      \
            gb01 = ho * w01[k] + gb01;                                        \
            gb23 = ho * w23[k] + gb23;                                        \
        }                                                                     \
        const v2f g01 = ga01 + gb01;                                          \
        const v2f g23 = ga23 + gb23;                                          \
        const v2f e01 = (v2f){ex2(g01[0]), ex2(g01[1])} + (v2f)(1.0f);        \
        const v2f e23 = (v2f){ex2(g23[0]), ex2(g23[1])} + (v2f)(1.0f);        \
        const float iv = rcpf(e01[0]);                                        \
        const float fv = rcpf(e01[1]);                                        \
        const float tg = __builtin_fmaf(2.0f, rcpf(e23[0]), -1.0f);           \
        const float ov = rcpf(e23[1]);                                        \
        c = __builtin_fmaf(fv, c, iv * tg);                                   \
        /* deferred fc: y(t-1) from live ha = h(t-1); fills tanh(c) shadow */ \
        float y = fb;                                                         \
        _Pragma("unroll")                                                     \
        for (int k = 0; k < 10; ++k) y = __builtin_fmaf(fw[k], ha[k], y);     \
        if (q == 0 && (TT) > 0) out[(IDX) - BATCH] = y;                       \
        const float ec = ex2(c * (-2.0f * L2E)) + 1.0f;                       \
        const float th = __builtin_fmaf(2.0f, rcpf(ec), -1.0f);               \
        const float hv = ov * th;                                             \
        h_sh[grp][q] = hv;                                                    \
        const float4 h03 = *reinterpret_cast<const float4*>(&h_sh[grp][0]);   \
        const float4 h47 = *reinterpret_cast<const float4*>(&h_sh[grp][4]);   \
        const float2 h89 = *reinterpret_cast<const float2*>(&h_sh[grp][8]);   \
        ha[0] = h03.x; ha[1] = h03.y; ha[2] = h03.z; ha[3] = h03.w;           \
        ha[4] = h47.x; ha[5] = h47.y; ha[6] = h47.z; ha[7] = h47.w;           \
        ha[8] = h89.x; ha[9] = h89.y;                                         \
    }

#pragma unroll 1
    for (int t = 0; t < SEQ; t += 2) {
        // prefetch x(t+2) (used as XA two steps from now; ~2 iters of cover)
        const size_t ipA = ix + 2 * (size_t)BATCH;
        const float xpA = x[(t + 2 < SEQ) ? ipA : ix];
        BODY(xA, ix, t);
        xA = xpA;

        const size_t ix1 = ix + BATCH;
        const size_t ipB = ix1 + 2 * (size_t)BATCH;
        const float xpB = x[(t + 3 < SEQ) ? ipB : ix1];
        BODY(xB, ix1, t + 1);
        xB = xpB;

        ix += 2 * (size_t)BATCH;
    }

    // epilogue: y(SEQ-1) from final ha = h(SEQ-1)
    {
        float y = fb;
#pragma unroll
        for (int k = 0; k < 10; ++k) y = __builtin_fmaf(fw[k], ha[k], y);
        if (q == 0) out[(size_t)(SEQ - 1) * BATCH + b] = y;
    }
#undef BODY
}

extern "C" void kernel_launch(void* const* d_in, const int* in_sizes, int n_in,
                              void* d_out, int out_size, void* d_ws, size_t ws_size,
                              hipStream_t stream) {
    const float* x    = (const float*)d_in[0];
    const float* w_ih = (const float*)d_in[1];
    const float* w_hh = (const float*)d_in[2];
    const float* b_ih = (const float*)d_in[3];
    const float* b_hh = (const float*)d_in[4];
    const float* fc_w = (const float*)d_in[5];
    const float* fc_b = (const float*)d_in[6];
    float* out = (float*)d_out;

    dim3 grid(BATCH / 16);   // 256 blocks, 16 batch elements (groups) each
    dim3 block(256);
    lstm_scan_kernel<<<grid, block, 0, stream>>>(x, w_ih, w_hh, b_ih, b_hh,
                                                 fc_w, fc_b, out);
}

// Round 4
// 583.871 us; speedup vs baseline: 1.3217x; 1.2795x over previous
//
#include <hip/hip_runtime.h>

// LSTM scan: S=2048, B=4096, IN=1, H=10.
// 16 lanes per batch element; lane j owns hidden unit j. Wave64 = 4 elems.
// Round-4 change vs round-3 (747us, VALUBusy 33%, VGPR=44):
//   VGPR_Count=44 proves the compiler REMATERIALIZES weight loads inside the
//   2048-step loop (>=80 loop-invariant floats can't fit in 44 regs); the
//   L1/L2-hit latency (~200cy) of those reloads sits in the per-step critical
//   chain. Fix: pin all loop-invariant values in VGPRs via empty asm
//   ("+v") so they cannot be rematerialized. Everything else as round 3
//   (pre-scaled weights, deferred fc, depth-2 x prefetch).

#define SEQ   2048
#define BATCH 4096

__device__ __forceinline__ float rcpf(float v) { return __builtin_amdgcn_rcpf(v); }
__device__ __forceinline__ float ex2(float v)  { return __builtin_amdgcn_exp2f(v); }

__global__ __launch_bounds__(256) void lstm_scan_kernel(
    const float* __restrict__ x,     // [S, B]
    const float* __restrict__ w_ih,  // [40, 1]
    const float* __restrict__ w_hh,  // [40, 10]
    const float* __restrict__ b_ih,  // [40]
    const float* __restrict__ b_hh,  // [40]
    const float* __restrict__ fc_w,  // [10]
    const float* __restrict__ fc_b,  // [1]
    float* __restrict__ out)         // [S, B]
{
    __shared__ float h_sh[16][16];   // [group][padded h row], 64B rows

    const int tid = threadIdx.x;
    const int grp = tid >> 4;        // 0..15 group within block
    const int q   = tid & 15;        // lane within group
    const int b   = (blockIdx.x << 4) + grp;   // batch element
    const int qq  = (q < 10) ? q : 0;          // lanes 10..15 duplicate j=0

    const float L2E = 1.44269504088896f;
    // rows: i=qq, f=10+qq, g=20+qq, o=30+qq. Pre-scale sigmoid rows by -L2E,
    // tanh (g) row by -2*L2E, so activation is rcp(1+exp2(gate)).
    const int r0 = qq, r1 = 10 + qq, r2 = 20 + qq, r3 = 30 + qq;
    const float s0 = -L2E, s1 = -L2E, s2 = -2.0f * L2E, s3 = -L2E;

    float wh0[10], wh1[10], wh2[10], wh3[10];
#pragma unroll
    for (int k = 0; k < 10; ++k) {
        wh0[k] = s0 * w_hh[r0 * 10 + k];
        wh1[k] = s1 * w_hh[r1 * 10 + k];
        wh2[k] = s2 * w_hh[r2 * 10 + k];
        wh3[k] = s3 * w_hh[r3 * 10 + k];
    }
    float wi0 = s0 * w_ih[r0], wi1 = s1 * w_ih[r1];
    float wi2 = s2 * w_ih[r2], wi3 = s3 * w_ih[r3];
    float bi0 = s0 * (b_ih[r0] + b_hh[r0]);
    float bi1 = s1 * (b_ih[r1] + b_hh[r1]);
    float bi2 = s2 * (b_ih[r2] + b_hh[r2]);
    float bi3 = s3 * (b_ih[r3] + b_hh[r3]);
    float fw[10];
#pragma unroll
    for (int k = 0; k < 10; ++k) fw[k] = fc_w[k];
    float fb = fc_b[0];

    // ---- PIN loop invariants in VGPRs (block rematerialization) ----
#pragma unroll
    for (int k = 0; k < 10; ++k) {
        asm("" : "+v"(wh0[k]), "+v"(wh1[k]), "+v"(wh2[k]), "+v"(wh3[k]));
        asm("" : "+v"(fw[k]));
    }
    asm("" : "+v"(wi0), "+v"(wi1), "+v"(wi2), "+v"(wi3));
    asm("" : "+v"(bi0), "+v"(bi1), "+v"(bi2), "+v"(bi3));
    asm("" : "+v"(fb));

    // ---- state ----
    float c = 0.0f;
    float ha[10];
#pragma unroll
    for (int k = 0; k < 10; ++k) ha[k] = 0.0f;

    // depth-2 x prefetch state
    size_t ix = (size_t)b;               // x index of current even step
    float xA = x[ix];                    // x(t)
    float xB = x[ix + BATCH];            // x(t+1)

#define BODY(XV, IDX, TT)                                                     \
    {                                                                         \
        const float xv = (XV);                                                \
        float g0a = __builtin_fmaf(wi0, xv, bi0), g0b = 0.0f;                 \
        float g1a = __builtin_fmaf(wi1, xv, bi1), g1b = 0.0f;                 \
        float g2a = __builtin_fmaf(wi2, xv, bi2), g2b = 0.0f;                 \
        float g3a = __builtin_fmaf(wi3, xv, bi3), g3b = 0.0f;                 \
        _Pragma("unroll")                                                     \
        for (int k = 0; k < 10; k += 2) {                                     \
            g0a = __builtin_fmaf(wh0[k], ha[k], g0a);                         \
            g1a = __builtin_fmaf(wh1[k], ha[k], g1a);                         \
            g2a = __builtin_fmaf(wh2[k], ha[k], g2a);                         \
            g3a = __builtin_fmaf(wh3[k], ha[k], g3a);                         \
        }                                                                     \
        _Pragma("unroll")                                                     \
        for (int k = 1; k < 10; k += 2) {                                     \
            g0b = __builtin_fmaf(wh0[k], ha[k], g0b);                         \
            g1b = __builtin_fmaf(wh1[k], ha[k], g1b);                         \
            g2b = __builtin_fmaf(wh2[k], ha[k], g2b);                         \
            g3b = __builtin_fmaf(wh3[k], ha[k], g3b);                         \
        }                                                                     \
        const float e0 = ex2(g0a + g0b) + 1.0f;                               \
        const float e1 = ex2(g1a + g1b) + 1.0f;                               \
        const float e2 = ex2(g2a + g2b) + 1.0f;                               \
        const float e3 = ex2(g3a + g3b) + 1.0f;                               \
        const float iv = rcpf(e0);                                            \
        const float fv = rcpf(e1);                                            \
        const float tg = __builtin_fmaf(2.0f, rcpf(e2), -1.0f);               \
        const float ov = rcpf(e3);                                            \
        c = __builtin_fmaf(fv, c, iv * tg);                                   \
        /* deferred fc: y(t-1) from live ha = h(t-1); fills tanh(c) shadow */ \
        float y = fb;                                                         \
        _Pragma("unroll")                                                     \
        for (int k = 0; k < 10; ++k) y = __builtin_fmaf(fw[k], ha[k], y);     \
        if (q == 0 && (TT) > 0) out[(IDX) - BATCH] = y;                       \
        const float ec = ex2(c * (-2.0f * L2E)) + 1.0f;                       \
        const float th = __builtin_fmaf(2.0f, rcpf(ec), -1.0f);               \
        const float hv = ov * th;                                             \
        h_sh[grp][q] = hv;                                                    \
        const float4 h03 = *reinterpret_cast<const float4*>(&h_sh[grp][0]);   \
        const float4 h47 = *reinterpret_cast<const float4*>(&h_sh[grp][4]);   \
        const float2 h89 = *reinterpret_cast<const float2*>(&h_sh[grp][8]);   \
        ha[0] = h03.x; ha[1] = h03.y; ha[2] = h03.z; ha[3] = h03.w;           \
        ha[4] = h47.x; ha[5] = h47.y; ha[6] = h47.z; ha[7] = h47.w;           \
        ha[8] = h89.x; ha[9] = h89.y;                                         \
    }

#pragma unroll 1
    for (int t = 0; t < SEQ; t += 2) {
        // prefetch x(t+2) (used two steps from now; ~2 iters of latency cover)
        const size_t ipA = ix + 2 * (size_t)BATCH;
        const float xpA = x[(t + 2 < SEQ) ? ipA : ix];
        BODY(xA, ix, t);
        xA = xpA;

        const size_t ix1 = ix + BATCH;
        const size_t ipB = ix1 + 2 * (size_t)BATCH;
        const float xpB = x[(t + 3 < SEQ) ? ipB : ix1];
        BODY(xB, ix1, t + 1);
        xB = xpB;

        ix += 2 * (size_t)BATCH;
    }

    // epilogue: y(SEQ-1) from final ha = h(SEQ-1)
    {
        float y = fb;
#pragma unroll
        for (int k = 0; k < 10; ++k) y = __builtin_fmaf(fw[k], ha[k], y);
        if (q == 0) out[(size_t)(SEQ - 1) * BATCH + b] = y;
    }
#undef BODY
}

extern "C" void kernel_launch(void* const* d_in, const int* in_sizes, int n_in,
                              void* d_out, int out_size, void* d_ws, size_t ws_size,
                              hipStream_t stream) {
    const float* x    = (const float*)d_in[0];
    const float* w_ih = (const float*)d_in[1];
    const float* w_hh = (const float*)d_in[2];
    const float* b_ih = (const float*)d_in[3];
    const float* b_hh = (const float*)d_in[4];
    const float* fc_w = (const float*)d_in[5];
    const float* fc_b = (const float*)d_in[6];
    float* out = (float*)d_out;

    dim3 grid(BATCH / 16);   // 256 blocks, 16 batch elements (groups) each
    dim3 block(256);
    lstm_scan_kernel<<<grid, block, 0, stream>>>(x, w_ih, w_hh, b_ih, b_hh,
                                                 fc_w, fc_b, out);
}

// Round 6
// 580.499 us; speedup vs baseline: 1.3294x; 1.0058x over previous
//
#include <hip/hip_runtime.h>

// LSTM scan: S=2048, B=4096, IN=1, H=10.
// 16 lanes per batch element; lane j owns hidden unit j. Wave64 = 4 elems.
// Round-5 change vs round-4 (584us, VALUBusy 59%, VGPR=48):
//   Round-4's VGPR=48 proves the weights STILL aren't register-resident: the
//   default __launch_bounds__(256) lets the allocator target ~8 waves/SIMD
//   (~48-64 VGPR budget) and park the pinned weights in scratch, reloading
//   each iteration. We only ever run 1 wave/SIMD (Occupancy=12%), so:
//   __launch_bounds__(256, 1) -> full 256-VGPR budget, weights stay in regs.
//   Everything else identical to round 4 for clean attribution.
//   (Round-5 submission hit GPUAcquisitionTimeout — resubmitted unchanged.)

#define SEQ   2048
#define BATCH 4096

__device__ __forceinline__ float rcpf(float v) { return __builtin_amdgcn_rcpf(v); }
__device__ __forceinline__ float ex2(float v)  { return __builtin_amdgcn_exp2f(v); }

__global__ __launch_bounds__(256, 1) void lstm_scan_kernel(
    const float* __restrict__ x,     // [S, B]
    const float* __restrict__ w_ih,  // [40, 1]
    const float* __restrict__ w_hh,  // [40, 10]
    const float* __restrict__ b_ih,  // [40]
    const float* __restrict__ b_hh,  // [40]
    const float* __restrict__ fc_w,  // [10]
    const float* __restrict__ fc_b,  // [1]
    float* __restrict__ out)         // [S, B]
{
    __shared__ float h_sh[16][16];   // [group][padded h row], 64B rows

    const int tid = threadIdx.x;
    const int grp = tid >> 4;        // 0..15 group within block
    const int q   = tid & 15;        // lane within group
    const int b   = (blockIdx.x << 4) + grp;   // batch element
    const int qq  = (q < 10) ? q : 0;          // lanes 10..15 duplicate j=0

    const float L2E = 1.44269504088896f;
    // rows: i=qq, f=10+qq, g=20+qq, o=30+qq. Pre-scale sigmoid rows by -L2E,
    // tanh (g) row by -2*L2E, so activation is rcp(1+exp2(gate)).
    const int r0 = qq, r1 = 10 + qq, r2 = 20 + qq, r3 = 30 + qq;
    const float s0 = -L2E, s1 = -L2E, s2 = -2.0f * L2E, s3 = -L2E;

    float wh0[10], wh1[10], wh2[10], wh3[10];
#pragma unroll
    for (int k = 0; k < 10; ++k) {
        wh0[k] = s0 * w_hh[r0 * 10 + k];
        wh1[k] = s1 * w_hh[r1 * 10 + k];
        wh2[k] = s2 * w_hh[r2 * 10 + k];
        wh3[k] = s3 * w_hh[r3 * 10 + k];
    }
    float wi0 = s0 * w_ih[r0], wi1 = s1 * w_ih[r1];
    float wi2 = s2 * w_ih[r2], wi3 = s3 * w_ih[r3];
    float bi0 = s0 * (b_ih[r0] + b_hh[r0]);
    float bi1 = s1 * (b_ih[r1] + b_hh[r1]);
    float bi2 = s2 * (b_ih[r2] + b_hh[r2]);
    float bi3 = s3 * (b_ih[r3] + b_hh[r3]);
    float fw[10];
#pragma unroll
    for (int k = 0; k < 10; ++k) fw[k] = fc_w[k];
    float fb = fc_b[0];

    // ---- PIN loop invariants in VGPRs (block rematerialization) ----
#pragma unroll
    for (int k = 0; k < 10; ++k) {
        asm("" : "+v"(wh0[k]), "+v"(wh1[k]), "+v"(wh2[k]), "+v"(wh3[k]));
        asm("" : "+v"(fw[k]));
    }
    asm("" : "+v"(wi0), "+v"(wi1), "+v"(wi2), "+v"(wi3));
    asm("" : "+v"(bi0), "+v"(bi1), "+v"(bi2), "+v"(bi3));
    asm("" : "+v"(fb));

    // ---- state ----
    float c = 0.0f;
    float ha[10];
#pragma unroll
    for (int k = 0; k < 10; ++k) ha[k] = 0.0f;

    // depth-2 x prefetch state
    size_t ix = (size_t)b;               // x index of current even step
    float xA = x[ix];                    // x(t)
    float xB = x[ix + BATCH];            // x(t+1)

#define BODY(XV, IDX, TT)                                                     \
    {                                                                         \
        const float xv = (XV);                                                \
        float g0a = __builtin_fmaf(wi0, xv, bi0), g0b = 0.0f;                 \
        float g1a = __builtin_fmaf(wi1, xv, bi1), g1b = 0.0f;                 \
        float g2a = __builtin_fmaf(wi2, xv, bi2), g2b = 0.0f;                 \
        float g3a = __builtin_fmaf(wi3, xv, bi3), g3b = 0.0f;                 \
        _Pragma("unroll")                                                     \
        for (int k = 0; k < 10; k += 2) {                                     \
            g0a = __builtin_fmaf(wh0[k], ha[k], g0a);                         \
            g1a = __builtin_fmaf(wh1[k], ha[k], g1a);                         \
            g2a = __builtin_fmaf(wh2[k], ha[k], g2a);                         \
            g3a = __builtin_fmaf(wh3[k], ha[k], g3a);                         \
        }                                                                     \
        _Pragma("unroll")                                                     \
        for (int k = 1; k < 10; k += 2) {                                     \
            g0b = __builtin_fmaf(wh0[k], ha[k], g0b);                         \
            g1b = __builtin_fmaf(wh1[k], ha[k], g1b);                         \
            g2b = __builtin_fmaf(wh2[k], ha[k], g2b);                         \
            g3b = __builtin_fmaf(wh3[k], ha[k], g3b);                         \
        }                                                                     \
        const float e0 = ex2(g0a + g0b) + 1.0f;                               \
        const float e1 = ex2(g1a + g1b) + 1.0f;                               \
        const float e2 = ex2(g2a + g2b) + 1.0f;                               \
        const float e3 = ex2(g3a + g3b) + 1.0f;                               \
        const float iv = rcpf(e0);                                            \
        const float fv = rcpf(e1);                                            \
        const float tg = __builtin_fmaf(2.0f, rcpf(e2), -1.0f);               \
        const float ov = rcpf(e3);                                            \
        c = __builtin_fmaf(fv, c, iv * tg);                                   \
        /* deferred fc: y(t-1) from live ha = h(t-1); fills tanh(c) shadow */ \
        float y = fb;                                                         \
        _Pragma("unroll")                                                     \
        for (int k = 0; k < 10; ++k) y = __builtin_fmaf(fw[k], ha[k], y);     \
        if (q == 0 && (TT) > 0) out[(IDX) - BATCH] = y;                       \
        const float ec = ex2(c * (-2.0f * L2E)) + 1.0f;                       \
        const float th = __builtin_fmaf(2.0f, rcpf(ec), -1.0f);               \
        const float hv = ov * th;                                             \
        h_sh[grp][q] = hv;                                                    \
        const float4 h03 = *reinterpret_cast<const float4*>(&h_sh[grp][0]);   \
        const float4 h47 = *reinterpret_cast<const float4*>(&h_sh[grp][4]);   \
        const float2 h89 = *reinterpret_cast<const float2*>(&h_sh[grp][8]);   \
        ha[0] = h03.x; ha[1] = h03.y; ha[2] = h03.z; ha[3] = h03.w;           \
        ha[4] = h47.x; ha[5] = h47.y; ha[6] = h47.z; ha[7] = h47.w;           \
        ha[8] = h89.x; ha[9] = h89.y;                                         \
    }

#pragma unroll 1
    for (int t = 0; t < SEQ; t += 2) {
        // prefetch x(t+2) (used two steps from now; ~2 iters of latency cover)
        const size_t ipA = ix + 2 * (size_t)BATCH;
        const float xpA = x[(t + 2 < SEQ) ? ipA : ix];
        BODY(xA, ix, t);
        xA = xpA;

        const size_t ix1 = ix + BATCH;
        const size_t ipB = ix1 + 2 * (size_t)BATCH;
        const float xpB = x[(t + 3 < SEQ) ? ipB : ix1];
        BODY(xB, ix1, t + 1);
        xB = xpB;

        ix += 2 * (size_t)BATCH;
    }

    // epilogue: y(SEQ-1) from final ha = h(SEQ-1)
    {
        float y = fb;
#pragma unroll
        for (int k = 0; k < 10; ++k) y = __builtin_fmaf(fw[k], ha[k], y);
        if (q == 0) out[(size_t)(SEQ - 1) * BATCH + b] = y;
    }
#undef BODY
}

extern "C" void kernel_launch(void* const* d_in, const int* in_sizes, int n_in,
                              void* d_out, int out_size, void* d_ws, size_t ws_size,
                              hipStream_t stream) {
    const float* x    = (const float*)d_in[0];
    const float* w_ih = (const float*)d_in[1];
    const float* w_hh = (const float*)d_in[2];
    const float* b_ih = (const float*)d_in[3];
    const float* b_hh = (const float*)d_in[4];
    const float* fc_w = (const float*)d_in[5];
    const float* fc_b = (const float*)d_in[6];
    float* out = (float*)d_out;

    dim3 grid(BATCH / 16);   // 256 blocks, 16 batch elements (groups) each
    dim3 block(256);
    lstm_scan_kernel<<<grid, block, 0, stream>>>(x, w_ih, w_hh, b_ih, b_hh,
                                                 fc_w, fc_b, out);
}